// Round 24
// baseline (909.942 us; speedup 1.0000x reference)
//
#include <hip/hip_runtime.h>
#include <math.h>

#define TT 128
#define NN 256

typedef __attribute__((ext_vector_type(8))) short short8;
typedef __attribute__((ext_vector_type(8))) _Float16 half8;
typedef __attribute__((ext_vector_type(4))) float f32x4;

#define LOG2E 1.44269504088896340736f

// Fast transcendentals via hw v_exp_f32 (2^x) + v_rcp_f32 (~1ulp each; the
// library expf/tanhf carry 12-20+ instr edge handling — round-22 A/B: -94us).
__device__ __forceinline__ float exp2_(float x){ return __builtin_amdgcn_exp2f(x); }
__device__ __forceinline__ float rcp_(float x){ return __builtin_amdgcn_rcpf(x); }
__device__ __forceinline__ float sig_(float x){
  return rcp_(1.f + exp2_(-LOG2E*x));
}
__device__ __forceinline__ float tanh_(float x){
  const float e = exp2_(2.f*LOG2E*fabsf(x));     // e^{2|x|}
  const float t = 1.f - 2.f*rcp_(e + 1.f);
  return copysignf(t, x);
}
__device__ __forceinline__ float bf2f(unsigned int u){ return __uint_as_float(u<<16); }
// Integer RNE f32->bf16 (3 ops; faster than __bf16 cast which LLVM lowers
// with NaN-quieting — round-6/8 A/B: cast cost +141us total).
__device__ __forceinline__ unsigned short f2bf(float x){
  unsigned int u = __float_as_uint(x);
  u += 0x7fffu + ((u>>16)&1u);   // RNE
  return (unsigned short)(u>>16);
}
// fp32 <-> fp16 (native cvt instructions)
__device__ __forceinline__ unsigned short f2h(float x){
  _Float16 h = (_Float16)x;
  return __builtin_bit_cast(unsigned short, h);
}
__device__ __forceinline__ float h2f(unsigned short u){
  _Float16 h = __builtin_bit_cast(_Float16, u);
  return (float)h;
}
// Packed pair fp32 -> 2x fp16 (RTZ) in one instruction
__device__ __forceinline__ unsigned int cvtpk_f16(float a, float b){
  unsigned int r;
  asm("v_cvt_pkrtz_f16_f32 %0, %1, %2" : "=v"(r) : "v"(a), "v"(b));
  return r;
}

// Async global->LDS, 16B per lane (proven swizzle pair, rounds 11-23).
// GLOBAL source address is per-lane (enables the row-gather).
__device__ __forceinline__ void gld_lds16(const unsigned short* g, unsigned short* l){
  __builtin_amdgcn_global_load_lds(
      (const __attribute__((address_space(1))) unsigned int*)(g),
      (__attribute__((address_space(3))) unsigned int*)(l), 16, 0, 0);
}

// LLC-coherent (cross-XCD) access: sc0 sc1 bypasses L1+L2, coherence at Infinity Cache.
__device__ __forceinline__ short8 ld_llc8s(const unsigned short* p){
  f32x4 r;
  asm volatile("global_load_dwordx4 %0, %1, off sc0 sc1" : "=v"(r) : "v"(p) : "memory");
  return __builtin_bit_cast(short8, r);
}
__device__ __forceinline__ void st_llc_s(unsigned short* p, unsigned short v){
  unsigned int vv = v;
  asm volatile("global_store_short %0, %1, off sc0 sc1" :: "v"(p), "v"(vv) : "memory");
}

// ---------------------------------------------------------------------------
// Dead-row compaction map: rows (t,n) with t >= lengths[n] are never read by
// the final gather (h at last, mem at last) — ~50% of post-scan work for
// uniform lengths. Build a (n,t)-sorted compact index:
//   rowmap[base[n]+t] = NN + t*NN + n   (ccb CUR row; prev = -NN)
//   mliv[0] = M' = sum(lengths); mliv[1] = Mpad = roundup(M',128)
//   rowmap[M'..32768) = NN (dummy -> finite data; outputs land in unread pos)
// Single block; graph-capture safe (grids stay worst-case, map is device-side).
// ---------------------------------------------------------------------------
__global__ __launch_bounds__(256) void build_map(const int* __restrict__ lengths,
    int* __restrict__ base, int* __restrict__ mliv, int* __restrict__ rowmap)
{
  const int tid = threadIdx.x;
  __shared__ int sl[256];
  __shared__ int sbase[257];
  sl[tid] = lengths[tid];
  __syncthreads();
  if (tid == 0){
    int acc = 0;
    for (int n=0;n<256;n++){ sbase[n] = acc; acc += sl[n]; }
    sbase[256] = acc;
    mliv[0] = acc;
    mliv[1] = (acc + 127) & ~127;
  }
  __syncthreads();
  base[tid] = sbase[tid];
  const int b0 = sbase[tid];
  const int len = sl[tid];
  for (int t=0;t<len;t++) rowmap[b0+t] = NN + t*NN + tid;
  const int M = sbase[256];
  for (int p = M + tid; p < TT*NN; p += 256) rowmap[p] = NN;
}

// ---------------------------------------------------------------------------
// fp32 NT GEMM (only the tiny output MLP now)
// ---------------------------------------------------------------------------
template<int BM,int BN,int ACT>
__global__ __launch_bounds__(256) void gemm_nt(const float* __restrict__ A,
    const float* __restrict__ W, const float* __restrict__ b1,
    const float* __restrict__ b2, float* __restrict__ C,
    int M, int K, int Nc)
{
  constexpr int TM = BM/16, TN = BN/16;
  __shared__ float As[BM*32];
  __shared__ float Bs[BN*32];
  const int tid = threadIdx.x;
  const int n0 = blockIdx.x*BN, m0 = blockIdx.y*BM;
  const int tx = tid & 15, ty = tid >> 4;
  float acc[TM][TN];
  #pragma unroll
  for (int r=0;r<TM;r++)
    #pragma unroll
    for (int c=0;c<TN;c++) acc[r][c]=0.f;
  const int swA = (ty & 7) << 2;
  const int swB = (tx & 7) << 2;
  for (int k0=0;k0<K;k0+=32){
    #pragma unroll
    for (int f=tid; f<BM*8; f+=256){
      const int row=f>>3, kq=f&7;
      float4 v = *(const float4*)(A + (size_t)(m0+row)*K + k0 + (kq<<2));
      *(float4*)(&As[row*32 + ((kq<<2) ^ ((row&7)<<2))]) = v;
    }
    #pragma unroll
    for (int f=tid; f<BN*8; f+=256){
      const int row=f>>3, kq=f&7;
      float4 v = *(const float4*)(W + (size_t)(n0+row)*K + k0 + (kq<<2));
      *(float4*)(&Bs[row*32 + ((kq<<2) ^ ((row&7)<<2))]) = v;
    }
    __syncthreads();
    #pragma unroll
    for (int kq=0;kq<8;kq++){
      const int k = kq<<2;
      float4 av[TM], bv[TN];
      #pragma unroll
      for (int r=0;r<TM;r++){ const int row=ty+16*r; av[r] = *(const float4*)(&As[row*32 + (k ^ swA)]); }
      #pragma unroll
      for (int c=0;c<TN;c++){ const int col=tx+16*c; bv[c] = *(const float4*)(&Bs[col*32 + (k ^ swB)]); }
      #pragma unroll
      for (int r=0;r<TM;r++)
        #pragma unroll
        for (int c=0;c<TN;c++){
          acc[r][c] += av[r].x*bv[c].x;
          acc[r][c] += av[r].y*bv[c].y;
          acc[r][c] += av[r].z*bv[c].z;
          acc[r][c] += av[r].w*bv[c].w;
        }
    }
    __syncthreads();
  }
  #pragma unroll
  for (int c=0;c<TN;c++){
    const int gcol = n0 + tx + 16*c;
    const float bias = (b1 ? b1[gcol] : 0.f) + (b2 ? b2[gcol] : 0.f);
    #pragma unroll
    for (int r=0;r<TM;r++){
      const int grow = m0 + ty + 16*r;
      float v = acc[r][c] + bias;
      if (ACT==1) v = fmaxf(v, 0.f);
      C[(size_t)grow*Nc + gcol] = v;
    }
  }
}

// ---------------------------------------------------------------------------
// bf16 MFMA NT GEMM (post-scan MLPs): C = act(A@Wb^T + bias)
// Staging via global_load_lds width-16 (proven swizzle pair, rounds 11-23).
// XCD-aware block remap (T1). Dead-row compaction: blocks with m0 >= Mpad
// (mliv[1]) exit; AMAP=1 gathers A rows through rowmap (attn1's ccb concat:
// k0 < kswitch -> prev row = rowmap[m]-NN col k0; else cur row col k0-kswitch).
// ACT: 0 none, 1 relu, 2 sigmoid, 3 tanh, 4 col<512?sigmoid:tanh
// OBF: 0 fp32 out, 1 bf16 out, 2 fp16 out
// ---------------------------------------------------------------------------
template<int ACT,int OBF,int AMAP>
__global__ __launch_bounds__(256) void gemm_mfma(const unsigned short* __restrict__ A,
    const unsigned short* __restrict__ Wb, const float* __restrict__ bias,
    void* __restrict__ Cp, int M, int K, int Nc, int lda, int ldc, int aseg,
    int kswitch, int aextra,
    const int* __restrict__ rowmap, const int* __restrict__ mliv)
{
  __shared__ unsigned short sA[128*64];
  __shared__ unsigned short sB[128*64];
  const int tid = threadIdx.x;
  const int wave = tid >> 6, lane = tid & 63;
  // XCD-aware remap: lin -> (xcd, slot) -> (panel, xcol)
  const int nx = gridDim.x;
  const int lin = blockIdx.y*nx + blockIdx.x;
  const int xcd = lin & 7, s = lin >> 3;
  const int ppx = gridDim.y >> 3;                   // panels per XCD (=32)
  const int m0 = (xcd*ppx + s/nx)*128;
  const int n0 = (s % nx)*128;
  if (m0 >= mliv[1]) return;                        // dead panel (compact M)
  const unsigned short* Ab = A + (size_t)(n0 >> 8) * (size_t)aseg;  // block-uniform
  const int wm = (wave>>1)*64, wn = (wave&1)*64;
  const int r = lane & 15, g = lane >> 4;
  const int srow = wave*32 + (lane>>3);                  // + i*8
  const int scol = (((lane&7) ^ ((lane>>3)&7)) << 3);    // shorts
  int rml[4];
  if constexpr (AMAP){
    #pragma unroll
    for (int i=0;i<4;i++) rml[i] = rowmap[m0 + srow + i*8];
  }
  f32x4 acc[4][4];
  #pragma unroll
  for (int i=0;i<4;i++)
    #pragma unroll
    for (int j=0;j<4;j++) acc[i][j] = (f32x4){0.f,0.f,0.f,0.f};

  for (int k0 = 0; k0 < K; k0 += 64){
    if constexpr (AMAP){
      const int sel  = (k0 < kswitch);
      const int cb   = sel ? k0 : (k0 - kswitch);
      const int radj = sel ? -NN : 0;
      #pragma unroll
      for (int i=0;i<4;i++)
        gld_lds16(A + (size_t)(rml[i]+radj)*lda + cb + scol, &sA[wave*2048 + i*512]);
    } else {
      const size_t aoff = (size_t)k0 + ((k0 >= kswitch) ? (size_t)aextra : 0);
      #pragma unroll
      for (int i=0;i<4;i++)
        gld_lds16(Ab + (size_t)(m0+srow+i*8)*lda + aoff + scol, &sA[wave*2048 + i*512]);
    }
    #pragma unroll
    for (int i=0;i<4;i++)
      gld_lds16(Wb + (size_t)(n0+srow+i*8)*K + k0 + scol, &sB[wave*2048 + i*512]);
    asm volatile("s_waitcnt vmcnt(0)" ::: "memory");
    __syncthreads();
    #pragma unroll
    for (int ks=0; ks<2; ks++){
      const int cofs = ((ks*32 + g*8) ^ ((r&7)<<3));
      short8 af[4], bfr[4];
      #pragma unroll
      for (int mi=0;mi<4;mi++) af[mi]  = *(const short8*)(&sA[(wm+mi*16+r)*64 + cofs]);
      #pragma unroll
      for (int ni=0;ni<4;ni++) bfr[ni] = *(const short8*)(&sB[(wn+ni*16+r)*64 + cofs]);
      #pragma unroll
      for (int mi=0;mi<4;mi++)
        #pragma unroll
        for (int ni=0;ni<4;ni++)
          acc[mi][ni] = __builtin_amdgcn_mfma_f32_16x16x32_bf16(af[mi], bfr[ni], acc[mi][ni], 0, 0, 0);
    }
    __syncthreads();
  }
  #pragma unroll
  for (int mi=0;mi<4;mi++)
    #pragma unroll
    for (int ni=0;ni<4;ni++){
      const int col_l = wn + ni*16 + r;
      const float b = bias[n0 + col_l];
      #pragma unroll
      for (int reg=0;reg<4;reg++){
        const int row = m0 + wm + mi*16 + g*4 + reg;
        float v = acc[mi][ni][reg] + b;
        if (ACT==1) v = fmaxf(v,0.f);
        else if (ACT==2) v = sig_(v);
        else if (ACT==3) v = tanh_(v);
        else if (ACT==4) v = (n0 + col_l < 512) ? sig_(v) : tanh_(v);
        if (OBF==1)      ((unsigned short*)Cp)[(size_t)row*ldc + n0 + col_l] = f2bf(v);
        else if (OBF==2) ((unsigned short*)Cp)[(size_t)row*ldc + n0 + col_l] = f2h(v);
        else             ((float*)Cp)[(size_t)row*ldc + n0 + col_l] = v;
      }
    }
}

// ---------------------------------------------------------------------------
// Fused fp16 projection GEMMs + post-scan f2bf weight converts.
// Blocks: [0,2048) text (Nc=1024, K=768) | [2048,3072) audio (512,128) |
//         [3072,4096) vision (512,512)  | [4096,7040) f2bf converts.
// P output: fp16 GATE-INTERLEAVED — element (row, col) stored at
// [row][ (col & (H-1))*4 + (col>>log2H) ], so the 4 gate values of one
// (row, jcol) are one contiguous 8B uint2 (scan loads them in ONE dwordx2).
// ---------------------------------------------------------------------------
__global__ __launch_bounds__(256) void proj_all(
    const float* __restrict__ xt, const float* __restrict__ xa, const float* __restrict__ xv,
    const unsigned short* __restrict__ wt, const unsigned short* __restrict__ wa,
    const unsigned short* __restrict__ wv,
    const float* __restrict__ bih_t, const float* __restrict__ bhh_t,
    const float* __restrict__ bih_a, const float* __restrict__ bhh_a,
    const float* __restrict__ bih_v, const float* __restrict__ bhh_v,
    unsigned short* __restrict__ Pt, unsigned short* __restrict__ Pa,
    unsigned short* __restrict__ Pv,
    const float* __restrict__ aw1, const float* __restrict__ aw2,
    const float* __restrict__ g1w1, const float* __restrict__ g2w1,
    const float* __restrict__ uw1, const float* __restrict__ g1w2,
    const float* __restrict__ g2w2, const float* __restrict__ uw2,
    unsigned short* __restrict__ wbp)
{
  __shared__ unsigned short sA[128*72];
  __shared__ unsigned short sB[128*64];
  const int tid = threadIdx.x;
  const int blk = blockIdx.x;
  if (blk >= 4096){
    // ---- f2bf: fp32 weight -> bf16 (contiguous pool), post-scan use only ----
    const int cb = blk - 4096;
    const float* src; unsigned short* dst; int i;
    if (cb < 2560){
      const int s = cb >> 9, lb = cb & 511;
      src = (s==0)?aw1:(s==1)?aw2:(s==2)?g1w1:(s==3)?g2w1:uw1;
      dst = wbp + (size_t)s*524288;
      i = lb*256 + tid;
    } else {
      const int s = (cb-2560) >> 7, lb = (cb-2560) & 127;
      src = (s==0)?g1w2:(s==1)?g2w2:uw2;
      dst = wbp + 2621440 + (size_t)s*131072;
      i = lb*256 + tid;
    }
    const float4 v = ((const float4*)src)[i];
    ushort4 o;
    o.x=f2bf(v.x); o.y=f2bf(v.y); o.z=f2bf(v.z); o.w=f2bf(v.w);
    ((ushort4*)dst)[i] = o;
    return;
  }
  const int wave = tid >> 6, lane = tid & 63;
  const float* A; const unsigned short* Wf; const float *b1, *b2; unsigned short* C;
  int K, Nc, nbs, rel, shf;
  if (blk < 2048)      { rel=blk;      A=xt; Wf=wt; b1=bih_t; b2=bhh_t; C=Pt; K=768; Nc=1024; nbs=3; shf=8; }
  else if (blk < 3072) { rel=blk-2048; A=xa; Wf=wa; b1=bih_a; b2=bhh_a; C=Pa; K=128; Nc=512;  nbs=2; shf=7; }
  else                 { rel=blk-3072; A=xv; Wf=wv; b1=bih_v; b2=bhh_v; C=Pv; K=512; Nc=512;  nbs=2; shf=7; }
  // XCD-aware remap within the region (region base is 8-aligned)
  const int xcd = rel & 7, s = rel >> 3;
  const int nxc = 1 << nbs;                  // x-cols per panel (8 / 4 / 4)
  const int m0 = (xcd*32 + s/nxc)*128;       // 32 panels per XCD
  const int n0 = (s & (nxc-1))*128;
  const int wm = (wave>>1)*64, wn = (wave&1)*64;
  const int r = lane & 15, g = lane >> 4;
  const int srow = wave*32 + (lane>>3);
  const int scol = (((lane&7) ^ ((lane>>3)&7)) << 3);
  f32x4 acc[4][4];
  #pragma unroll
  for (int i=0;i<4;i++)
    #pragma unroll
    for (int j=0;j<4;j++) acc[i][j] = (f32x4){0.f,0.f,0.f,0.f};

  for (int k0 = 0; k0 < K; k0 += 64){
    // ---- B via async gload_lds (swizzled source, linear dest) ----
    #pragma unroll
    for (int i=0;i<4;i++)
      gld_lds16(Wf + (size_t)(n0+srow+i*8)*K + k0 + scol, &sB[wave*2048 + i*512]);
    // ---- A via reg staging with fp32->fp16 convert (pad-72) ----
    #pragma unroll
    for (int j=0;j<4;j++){
      const int slot = tid + j*256;
      const int row = slot>>3, seg = (slot&7)<<3;
      const float* ap = A + (size_t)(m0+row)*K + k0 + seg;
      const float4 v0 = *(const float4*)ap;
      const float4 v1 = *(const float4*)(ap+4);
      uint4 hv;
      hv.x = cvtpk_f16(v0.x, v0.y);
      hv.y = cvtpk_f16(v0.z, v0.w);
      hv.z = cvtpk_f16(v1.x, v1.y);
      hv.w = cvtpk_f16(v1.z, v1.w);
      *(uint4*)(&sA[row*72 + seg]) = hv;
    }
    asm volatile("s_waitcnt vmcnt(0)" ::: "memory");   // drain gload_lds
    __syncthreads();
    #pragma unroll
    for (int ks=0; ks<2; ks++){
      const int cofsB = ((ks*32 + g*8) ^ ((r&7)<<3));
      half8 af[4], bfr[4];
      #pragma unroll
      for (int mi=0;mi<4;mi++) af[mi]  = *(const half8*)(&sA[(wm+mi*16+r)*72 + ks*32 + g*8]);
      #pragma unroll
      for (int ni=0;ni<4;ni++) bfr[ni] = *(const half8*)(&sB[(wn+ni*16+r)*64 + cofsB]);
      #pragma unroll
      for (int mi=0;mi<4;mi++)
        #pragma unroll
        for (int ni=0;ni<4;ni++)
          acc[mi][ni] = __builtin_amdgcn_mfma_f32_16x16x32_f16(af[mi], bfr[ni], acc[mi][ni], 0, 0, 0);
    }
    __syncthreads();
  }
  const int jm = (1<<shf) - 1;
  #pragma unroll
  for (int mi=0;mi<4;mi++)
    #pragma unroll
    for (int ni=0;ni<4;ni++){
      const int col_l = wn + ni*16 + r;
      const int col = n0 + col_l;
      const float b = b1[col] + b2[col];
      const size_t cofs = (size_t)((col & jm)<<2) + (col>>shf);
      #pragma unroll
      for (int reg=0;reg<4;reg++){
        const int row = m0 + wm + mi*16 + g*4 + reg;
        C[(size_t)row*Nc + cofs] = f2h(acc[mi][ni][reg] + b);
      }
    }
}

// ---------------------------------------------------------------------------
// Fused prep kernel. Block-range:
//   [0,1088)      Wih fp16 converts (768 + 64 + 256)
//   [1088,1280)   Whh frag reorder -> SINGLE fp16 plane (128 + 32 + 32)
//   [1280,1615)   bcat1 (6) | bcat2 (3) | hf zero (256) | flags (6) | ccz (64)
// ---------------------------------------------------------------------------
__device__ __forceinline__ void wfrag_body(const float* __restrict__ W, int H,
    int e, unsigned short* __restrict__ ff)
{
  const int nch = H >> 5;
  const int lane = e & 63;
  int r = e >> 6;
  const int ks = r % nch; r /= nch;
  const int ct = r & 3; r >>= 2;
  const int jb = r;
  const int col = ct*H + jb*16 + (lane & 15);
  const int kb  = ks*32 + (lane >> 4)*8;
  #pragma unroll
  for (int j=0;j<8;j++){
    ff[(size_t)e*8 + j] = f2h(W[(size_t)col*H + kb + j]);
  }
}

__global__ __launch_bounds__(256) void prep_all(
    const float* __restrict__ Wih_t, const float* __restrict__ Wih_a,
    const float* __restrict__ Wih_v,
    const float* __restrict__ Whh_t, const float* __restrict__ Whh_a,
    const float* __restrict__ Whh_v,
    const float* __restrict__ g1b1, const float* __restrict__ g2b1,
    const float* __restrict__ ub1,
    const float* __restrict__ g1b2, const float* __restrict__ g2b2,
    const float* __restrict__ ub2,
    unsigned short* __restrict__ wbp, unsigned short* __restrict__ wfp,
    float* __restrict__ bcat1, float* __restrict__ bcat2,
    float* __restrict__ hfZ,
    unsigned int* __restrict__ flags, unsigned short* __restrict__ ccb)
{
  const int blk = blockIdx.x, tid = threadIdx.x;
  if (blk < 1088){
    // ---- Wih fp32 -> fp16 (single array per modality) ----
    const int rel = blk;
    const float* src; unsigned short* dst; int i;
    if (rel < 768)      { src=Wih_t; dst=wbp+3014656; i=rel*256+tid; }
    else if (rel < 832) { src=Wih_a; dst=wbp+3801088; i=(rel-768)*256+tid; }
    else                { src=Wih_v; dst=wbp+3866624; i=(rel-832)*256+tid; }
    const float4 v = ((const float4*)src)[i];
    ushort4 h;
    h.x=f2h(v.x); h.y=f2h(v.y); h.z=f2h(v.z); h.w=f2h(v.w);
    ((ushort4*)dst)[i] = h;
  } else if (blk < 1280){
    // ---- Whh MFMA-B-frag reorder (single fp16 plane) ----
    const int rel = blk - 1088;
    if (rel < 128)      wfrag_body(Whh_t, 256, rel*256+tid,       wfp);
    else if (rel < 160) wfrag_body(Whh_a, 128, (rel-128)*256+tid, wfp+262144);
    else                wfrag_body(Whh_v, 128, (rel-160)*256+tid, wfp+327680);
  } else {
    // ---- misc: bias concats + zeroing ----
    const int rel = blk - 1280;
    if (rel < 6){
      const int idx = rel*256 + tid;
      float v = (idx<512) ? g1b1[idx] : (idx<1024) ? g2b1[idx-512] : ub1[idx-1024];
      bcat1[idx] = v;
    } else if (rel < 9){
      const int idx = (rel-6)*256 + tid;
      float v = (idx<256) ? g1b2[idx] : (idx<512) ? g2b2[idx-256] : ub2[idx-512];
      bcat2[idx] = v;
    } else if (rel < 265){
      const int i = (rel-9)*256 + tid;
      ((float4*)hfZ)[i] = (float4){0.f,0.f,0.f,0.f};
    } else if (rel < 271){
      const int i = (rel-265)*256 + tid;
      ((uint4*)flags)[i] = (uint4){0u,0u,0u,0u};
    } else {
      // zero ccb pad rows (t = -1): NN*512 ushorts
      const int i = (rel-271)*256 + tid;
      ((uint4*)ccb)[i] = (uint4){0u,0u,0u,0u};
    }
  }
}

// ---------------------------------------------------------------------------
// Persistent LSTM scan (round-3 proven protocol). fp16 SINGLE-PLANE h +
// fp16 gate-interleaved P + hw-exp2 transcendentals. Byte-identical to the
// round-23 build (902us).
// ---------------------------------------------------------------------------
__global__ __launch_bounds__(256) void lstm_scan(
    const unsigned short* __restrict__ Pt, const unsigned short* __restrict__ Pa,
    const unsigned short* __restrict__ Pv,
    const unsigned short* __restrict__ wtfF, const unsigned short* __restrict__ wafF,
    const unsigned short* __restrict__ wvfF,
    const int* __restrict__ lengths,
    unsigned short* __restrict__ hfT, unsigned short* __restrict__ hfA, unsigned short* __restrict__ hfV,
    unsigned short* __restrict__ ccb, float* __restrict__ o_stage,
    unsigned int* __restrict__ flags)
{
  __shared__ unsigned short sWh[16384];   // 32 KB (text max: 4ct x 8ks x 64 x 8, fp16)
  __shared__ float sG[4*32*17];           // gate scratch, pad 17
  const int tid = threadIdx.x;
  const int b = blockIdx.x;
  const int rb = b & 7, jb = b >> 3;
  const int n0 = rb * 32;
  const unsigned short* P; const unsigned short* wfF; unsigned short* hf;
  int H, j0, off, grp, mem, gsz, jbl;
  if (jb < 16)      { P=Pt; wfF=wtfF; hf=hfT; H=256; jbl=jb;    off=0;   grp=rb;    mem=jbl; gsz=16; }
  else if (jb < 24) { P=Pa; wfF=wafF; hf=hfA; H=128; jbl=jb-16; off=256; grp=8+rb;  mem=jbl; gsz=8;  }
  else              { P=Pv; wfF=wvfF; hf=hfV; H=128; jbl=jb-24; off=384; grp=16+rb; mem=jbl; gsz=8;  }
  j0 = jbl*16;
  const int nch = H >> 5;
  const int G4 = 4*H;
  const size_t planeSz = (size_t)NN*H;    // ushorts per plane
  unsigned int* myflag = &flags[(grp*16+mem)<<4];
  unsigned int* gflags = &flags[(grp*16)<<4];

  // one-time W frag staging to LDS (contiguous copy, fp16 single plane)
  {
    const unsigned short* srcF = wfF + (size_t)jbl*4*nch*512;
    const int nseg = 4*nch*64;
    for (int s = tid; s < nseg; s += 256)
      *(uint4*)(&sWh[s*8]) = *(const uint4*)(srcF + (size_t)s*8);
  }
  const int tx = tid & 15, ty = tid >> 4;
  const int n_a = n0 + ty, n_b = n0 + ty + 16;
  const int last_a = lengths[n_a] - 1, last_b = lengths[n_b] - 1;
  const int jcol = j0 + tx;
  // producer h-frag element indices (within a plane)
  const int ksP = jcol >> 5, kqP = (jcol>>3)&3, jP = jcol&7;
  const size_t eA = ((size_t)((rb*2+0)*nch + ksP)*64 + (ty|(kqP<<4)))*8 + jP;   // row ty   (rt 0)
  const size_t eB = ((size_t)((rb*2+1)*nch + ksP)*64 + (ty|(kqP<<4)))*8 + jP;   // row ty+16(rt 1)
  const int wave = tid >> 6, lane = tid & 63;
  const int rt = wave >> 1, ct0 = (wave&1)*2, ct1 = ct0+1;
  const size_t fragBase = ((size_t)(rb*2+rt)*nch)*512 + (size_t)lane*8;   // + ks*512
  float c_a = 0.f, c_b = 0.f;
  uint2 pA, pB;
  {
    pA = *(const uint2*)(P + (size_t)n_a*G4 + (size_t)jcol*4);
    pB = *(const uint2*)(P + (size_t)n_b*G4 + (size_t)jcol*4);
  }
  __syncthreads();

  for (int t = 0; t < TT; ++t){
    const int cur = t & 1, nxt = cur ^ 1;
    const unsigned short* hH = hf + (size_t)cur*planeSz;
    // ---- A-frags direct from LLC into registers (single fp16 plane) ----
    short8 ah[8];
    #pragma unroll
    for (int ks=0; ks<8; ks++) if (ks < nch)
      ah[ks] = ld_llc8s(hH + fragBase + (size_t)ks*512);
    asm volatile("s_waitcnt vmcnt(0)" ::: "memory");
    // ---- early P prefetch for t+1 (ONE uint2 each): completes under MFMA ----
    uint2 pA2, pB2;
    if (t < TT-1){
      pA2 = *(const uint2*)(P + ((size_t)(t+1)*NN + n_a)*G4 + (size_t)jcol*4);
      pB2 = *(const uint2*)(P + ((size_t)(t+1)*NN + n_b)*G4 + (size_t)jcol*4);
    }
    __builtin_amdgcn_sched_barrier(0);   // pin prefetch issue before MFMA
    // ---- MFMA: gates tile 16x32 (2 col-tiles per wave, fp16) ----
    f32x4 acc0 = (f32x4){0.f,0.f,0.f,0.f}, acc1 = (f32x4){0.f,0.f,0.f,0.f};
    #pragma unroll
    for (int ks=0; ks<8; ks++) if (ks < nch){
      const int b0 = ((ct0*nch+ks)*64 + lane)*8;
      const int b1 = ((ct1*nch+ks)*64 + lane)*8;
      const half8 w0 = *(const half8*)(&sWh[b0]);
      const half8 w1 = *(const half8*)(&sWh[b1]);
      const half8 a  = __builtin_bit_cast(half8, ah[ks]);
      acc0 = __builtin_amdgcn_mfma_f32_16x16x32_f16(a, w0, acc0, 0,0,0);
      acc1 = __builtin_amdgcn_mfma_f32_16x16x32_f16(a, w1, acc1, 0,0,0);
    }
    // gate write: C row = (lane>>4)*4+reg, col = lane&15
    #pragma unroll
    for (int reg=0; reg<4; reg++){
      const int grow = rt*16 + (lane>>4)*4 + reg;
      sG[(ct0*32+grow)*17 + (lane&15)] = acc0[reg];
      sG[(ct1*32+grow)*17 + (lane&15)] = acc1[reg];
    }
    __syncthreads();
    // ---- cell update: only the h-frag stores issue here ----
    const size_t pbase = (size_t)t*NN;
    const int col = off + jcol;
    unsigned short cA, cB; float h2a, h2b;
    {
      unsigned short* dH = hf + (size_t)nxt*planeSz;
      float gi = sG[(0*32+ty)*17+tx] + h2f((unsigned short)(pA.x & 0xffffu));
      float gf = sG[(1*32+ty)*17+tx] + h2f((unsigned short)(pA.x >> 16));
      float gg = sG[(2*32+ty)*17+tx] + h2f((unsigned short)(pA.y & 0xffffu));
      float go = sG[(3*32+ty)*17+tx] + h2f((unsigned short)(pA.y >> 16));
      float c2 = sig_(gf)*c_a + sig_(gi)*tanh_(gg);
      c_a = c2;
      h2a = sig_(go)*tanh_(c2);
      st_llc_s(dH + eA, f2h(h2a));
      cA = f2bf(c2);

      gi = sG[(0*32+ty+16)*17+tx] + h2f((unsigned short)(pB.x & 0xffffu));
      gf = sG[(1*32+ty+16)*17+tx] + h2f((unsigned short)(pB.x >> 16));
      gg = sG[(2*32+ty+16)*17+tx] + h2f((unsigned short)(pB.y & 0xffffu));
      go = sG[(3*32+ty+16)*17+tx] + h2f((unsigned short)(pB.y >> 16));
      c2 = sig_(gf)*c_b + sig_(gi)*tanh_(gg);
      c_b = c2;
      h2b = sig_(go)*tanh_(c2);
      st_llc_s(dH + eB, f2h(h2b));
      cB = f2bf(c2);
    }
    // ---- per-group barrier through LLC (no cache maintenance) ----
    if (t < TT-1){
      const unsigned want = (unsigned)(t+1);
      asm volatile("s_waitcnt vmcnt(0)" ::: "memory");  // own h stores at LLC
      __syncthreads();
      if (tid == 0)
        __hip_atomic_store(myflag, want, __ATOMIC_RELAXED, __HIP_MEMORY_SCOPE_SYSTEM);
      // deferred ccb / o_stage stores: overlap with the poll (single cc write)
      ccb[(NN + pbase + n_a)*512 + col] = cA;
      if (t == last_a) o_stage[(size_t)n_a*768 + col] = h2a;
      ccb[(NN + pbase + n_b)*512 + col] = cB;
      if (t == last_b) o_stage[(size_t)n_b*768 + col] = h2b;
      __builtin_amdgcn_sched_barrier(0);
      if (tid < gsz){
        while (__hip_atomic_load(&gflags[tid<<4], __ATOMIC_RELAXED, __HIP_MEMORY_SCOPE_SYSTEM) < want)
          __builtin_amdgcn_s_sleep(1);
      }
      __syncthreads();
      pA = pA2; pB = pB2;
    } else {
      ccb[(NN + pbase + n_a)*512 + col] = cA;
      if (t == last_a) o_stage[(size_t)n_a*768 + col] = h2a;
      ccb[(NN + pbase + n_b)*512 + col] = cB;
      if (t == last_b) o_stage[(size_t)n_b*768 + col] = h2b;
    }
  }
}

// ---------------------------------------------------------------------------
// Row softmax over 1024 + multiply: ccs = cc_tt * softmax(logits), COMPACT
// rows. Row index = compact pos; cc read through rowmap (cur row; prev =
// cur - NN). Rows >= Mpad skipped.
// ---------------------------------------------------------------------------
__global__ __launch_bounds__(256) void softmax_mul(const unsigned short* __restrict__ logits,
    const unsigned short* __restrict__ ccb, unsigned short* __restrict__ outp,
    const int* __restrict__ rowmap, const int* __restrict__ mliv)
{
  const int row = blockIdx.x, tid = threadIdx.x;
  if (row >= mliv[1]) return;
  const size_t base = (size_t)row*1024 + (tid<<2);
  const ushort4 lv = *(const ushort4*)(logits + base);
  const float v0 = h2f(lv.x), v1 = h2f(lv.y), v2 = h2f(lv.z), v3 = h2f(lv.w);
  float m = fmaxf(fmaxf(v0,v1),fmaxf(v2,v3));
  #pragma unroll
  for (int o=32;o;o>>=1) m = fmaxf(m, __shfl_xor(m, o));
  __shared__ float sm[4]; __shared__ float ss[4];
  const int wid = tid>>6, lane = tid&63;
  if (lane==0) sm[wid]=m;
  __syncthreads();
  m = fmaxf(fmaxf(sm[0],sm[1]),fmaxf(sm[2],sm[3]));
  const float e0 = exp2_((v0-m)*LOG2E), e1 = exp2_((v1-m)*LOG2E);
  const float e2 = exp2_((v2-m)*LOG2E), e3 = exp2_((v3-m)*LOG2E);
  float s = e0+e1+e2+e3;
  #pragma unroll
  for (int o=32;o;o>>=1) s += __shfl_xor(s, o);
  if (lane==0) ss[wid]=s;
  __syncthreads();
  const float inv = rcp_(ss[0]+ss[1]+ss[2]+ss[3]);
  // mapped cc read: cols<512 -> prev ccb row; cols>=512 -> cur ccb row
  const int cur = rowmap[row];
  const size_t cbase = (tid < 128)
      ? ((size_t)(cur - NN)*512 + (tid<<2))
      : ((size_t)cur*512 + (tid<<2) - 512);
  const uint2 c2 = *(const uint2*)(ccb + cbase);
  const float c0 = bf2f(c2.x&0xffffu), c1 = bf2f(c2.x>>16);
  const float c2f= bf2f(c2.y&0xffffu), c3 = bf2f(c2.y>>16);
  uint2 o2;
  o2.x = (unsigned int)f2bf(c0*e0*inv) | ((unsigned int)f2bf(c1*e1*inv)<<16);
  o2.y = (unsigned int)f2bf(c2f*e2*inv) | ((unsigned int)f2bf(c3*e3*inv)<<16);
  *(uint2*)(outp + base) = o2;
}

// ---------------------------------------------------------------------------
// Memory recurrence over COMPACT rows: block n reads zo rows base[n]..+len-1
// (contiguous), runs exactly len steps; result is m at the last valid step.
// ---------------------------------------------------------------------------
__global__ __launch_bounds__(256) void mem_scan(const unsigned short* __restrict__ zo,
    const int* __restrict__ lengths, const int* __restrict__ base,
    float* __restrict__ o_stage)
{
  const int n = blockIdx.x, j = threadIdx.x;
  const int len = lengths[n];
  const size_t b0 = (size_t)base[n];
  float m = 0.f;
  for (int t0=0; t0<len; t0+=8){
    unsigned short a[8], bb[8], c[8];
    #pragma unroll
    for (int q=0;q<8;q++){
      const size_t row = (b0 + t0 + q)*768;   // may over-read into slot pad (safe)
      a[q]  = zo[row+j];
      bb[q] = zo[row+256+j];
      c[q]  = zo[row+512+j];
    }
    #pragma unroll
    for (int q=0;q<8;q++)
      if (t0+q < len) m = h2f(a[q])*m + h2f(bb[q])*h2f(c[q]);
  }
  o_stage[(size_t)n*768 + 512 + j] = m;
}

// ---------------------------------------------------------------------------
__global__ __launch_bounds__(256) void out_final(const float* __restrict__ hidden,
    const float* __restrict__ ow2, const float* __restrict__ ob2, float* __restrict__ out)
{
  const int n = blockIdx.x, tid = threadIdx.x;
  const float* hr = hidden + (size_t)n*768;
  float s = hr[tid]*ow2[tid] + hr[tid+256]*ow2[tid+256] + hr[tid+512]*ow2[tid+512];
  #pragma unroll
  for (int o=32;o;o>>=1) s += __shfl_xor(s, o);
  __shared__ float sw[4];
  const int wid=tid>>6, lane=tid&63;
  if (lane==0) sw[wid]=s;
  __syncthreads();
  if (tid==0) out[n] = sw[0]+sw[1]+sw[2]+sw[3] + ob2[0];
}

__global__ void ws_sentinel(float* out, float mb){ out[threadIdx.x] = mb; }

// ---------------------------------------------------------------------------
extern "C" void kernel_launch(void* const* d_in, const int* in_sizes, int n_in,
                              void* d_out, int out_size, void* d_ws, size_t ws_size,
                              hipStream_t stream)
{
  const float* x_text   = (const float*)d_in[0];
  const float* x_audio  = (const float*)d_in[1];
  const float* x_vision = (const float*)d_in[2];
  const int*   lengths  = (const int*)d_in[3];
  const float* Wih_t=(const float*)d_in[4],  *Whh_t=(const float*)d_in[5];
  const float* bih_t=(const float*)d_in[6],  *bhh_t=(const float*)d_in[7];
  const float* Wih_a=(const float*)d_in[8],  *Whh_a=(const float*)d_in[9];
  const float* bih_a=(const float*)d_in[10], *bhh_a=(const float*)d_in[11];
  const float* Wih_v=(const float*)d_in[12], *Whh_v=(const float*)d_in[13];
  const float* bih_v=(const float*)d_in[14], *bhh_v=(const float*)d_in[15];
  const float* aw1=(const float*)d_in[16], *ab1=(const float*)d_in[17];
  const float* aw2=(const float*)d_in[18], *ab2=(const float*)d_in[19];
  const float* g1w1=(const float*)d_in[20], *g1b1=(const float*)d_in[21];
  const float* g1w2=(const float*)d_in[22], *g1b2=(const float*)d_in[23];
  const float* g2w1=(const float*)d_in[24], *g2b1=(const float*)d_in[25];
  const float* g2w2=(const float*)d_in[26], *g2b2=(const float*)d_in[27];
  const float* uw1 =(const float*)d_in[28], *ub1 =(const float*)d_in[29];
  const float* uw2 =(const float*)d_in[30], *ub2 =(const float*)d_in[31];
  const float* ow1 =(const float*)d_in[32], *ob1 =(const float*)d_in[33];
  const float* ow2 =(const float*)d_in[34], *ob2 =(const float*)d_in[35];
  (void)in_sizes; (void)n_in; (void)out_size;

  // ---- workspace layout (float units). Peak ~350 MB ----
  const size_t oPt = 0;            // slot 33.55M : Pt(fp16 interleaved) -> logits(fp16) -> zcat(bf16)
  const size_t oPa = 33554432;     // slot 16.78M : Pa(fp16) -> z1(bf16) -> zo(fp16)
  const size_t oPv = 50331648;     // slot 16.78M : Pv(fp16) -> ccs(bf16)
  const size_t oCC = 67108864;     // 8.46M  : ccb [(T+1)*N, 512] bf16 (single-stored)
  const size_t oHF = 83886080;     // h frag pools (fp16 single-plane; half used)
  const size_t oOS = 84148224;     // 196608 : o_stage [256,768]
  const size_t oHID= 84344832;     // 196608
  const size_t oWB = 84541440;     // bf16/fp16 weight pool (2,621,440 f)
  const size_t oBC = 87162880;     // bcat1 1536 f + bcat2 768 f
  const size_t oBAR= 87165184;     // flags 6144 ints
  const size_t oWF = 87171328;     // Whh frag pool (fp16 single; half used)
  const size_t oMAP= 87564544;     // rowmap 32768 + base 256 + mliv 16 ints
  const size_t totalf = 87597584;

  if (ws_size < totalf * sizeof(float)) {
    ws_sentinel<<<1,256,0,stream>>>((float*)d_out, (float)(ws_size >> 20));
    return;
  }

  float* ws = (float*)d_ws;
  unsigned short* Pt = (unsigned short*)(ws + oPt);    // fp16 interleaved [32768,1024]
  unsigned short* Pa = (unsigned short*)(ws + oPa);    // fp16 interleaved [32768,512]
  unsigned short* Pv = (unsigned short*)(ws + oPv);    // fp16 interleaved [32768,512]
  unsigned short* ccb = (unsigned short*)(ws + oCC);   // [(T+1)*NN, 512] bf16
  unsigned short* hfT = (unsigned short*)(ws + oHF);            // [2 par][65536] fp16
  unsigned short* hfA = (unsigned short*)(ws + oHF + 131072);   // [2][32768]
  unsigned short* hfV = (unsigned short*)(ws + oHF + 196608);   // [2][32768]
  float* ost = ws + oOS; float* hid = ws + oHID;
  unsigned int* flags = (unsigned int*)(ws + oBAR);
  // weight pool (shorts)
  unsigned short* wbp   = (unsigned short*)(ws + oWB);
  unsigned short* aw1b  = wbp;                 // 524288
  unsigned short* aw2b  = wbp + 524288;        // 524288
  unsigned short* w1cat = wbp + 1048576;       // 1572864 (g1w1|g2w1|uw1)
  unsigned short* w2cat = wbp + 2621440;       // 393216 (g1w2|g2w2|uw2)
  unsigned short* wtih_f= wbp + 3014656;       // 786432 (fp16)
  unsigned short* waih_f= wbp + 3801088;       // 65536  (fp16)
  unsigned short* wvih_f= wbp + 3866624;       // 262144 (fp16, end 4128768)
  float* bcat1 = ws + oBC;
  float* bcat2 = ws + oBC + 1536;
  // Whh frag arrays (fp16 single-plane)
  unsigned short* wfp  = (unsigned short*)(ws + oWF);
  unsigned short* wtfF = wfp;                  // 262144
  unsigned short* wafF = wfp + 262144;         // 65536
  unsigned short* wvfF = wfp + 327680;         // 65536 (end 393216)
  // compaction map
  int* rowmap = (int*)(ws + oMAP);             // 32768
  int* basep  = rowmap + 32768;                // 256
  int* mliv   = basep + 256;                   // 16
  // post-scan aliases
  unsigned short* logits = (unsigned short*)(ws + oPt);   // fp16 (compact rows)
  unsigned short* z1     = (unsigned short*)(ws + oPa);
  unsigned short* ccs    = (unsigned short*)(ws + oPv);
  unsigned short* zcat   = (unsigned short*)(ws + oPt);
  unsigned short* zo     = (unsigned short*)(ws + oPa);   // fp16 [32768,768]

  dim3 blk(256);

  // prep kernel (Wih fp16, Whh fp16 frags, bias concats, zeroing)
  prep_all<<<1615,blk,0,stream>>>(Wih_t, Wih_a, Wih_v, Whh_t, Whh_a, Whh_v,
                                  g1b1, g2b1, ub1, g1b2, g2b2, ub2,
                                  wbp, wfp, bcat1, bcat2, (float*)hfT, flags, ccb);

  // dead-row compaction map (lengths only; ~50% of post-scan work eliminated)
  build_map<<<1,blk,0,stream>>>(lengths, basep, mliv, rowmap);

  // input projections (fp16 interleaved P out, XCD-swizzled) + f2bf converts
  proj_all<<<7040,blk,0,stream>>>(x_text, x_audio, x_vision,
                                  wtih_f, waih_f, wvih_f,
                                  bih_t, bhh_t, bih_a, bhh_a, bih_v, bhh_v,
                                  Pt, Pa, Pv,
                                  aw1, aw2, g1w1, g2w1, uw1, g1w2, g2w2, uw2,
                                  wbp);

  // sequential LSTM scan (fp16 MFMA + LLC frag exchange)
  {
    void* args[] = {(void*)&Pt,(void*)&Pa,(void*)&Pv,
                    (void*)&wtfF,(void*)&wafF,(void*)&wvfF,
                    (void*)&lengths,(void*)&hfT,(void*)&hfA,(void*)&hfV,
                    (void*)&ccb,(void*)&ost,(void*)&flags};
    hipError_t e = hipLaunchCooperativeKernel((const void*)lstm_scan,
                      dim3(256), dim3(256), args, 0, stream);
    if (e != hipSuccess)
      lstm_scan<<<256,blk,0,stream>>>(Pt,Pa,Pv,wtfF,wafF,wvfF,
                                      lengths,hfT,hfA,hfV,ccb,ost,flags);
  }

  // attention MLP on COMPACT rows (bf16 MFMA, gload_lds staging, XCD-swizzled).
  // attn1 gathers ccb via rowmap (AMAP=1): k<512 -> prev row (map-NN) col k;
  // k>=512 -> cur row col k-512. All others read compact intermediates.
  gemm_mfma<1,1,1><<<dim3(4,256),blk,0,stream>>>(ccb, aw1b, ab1, z1,     32768, 1024, 512,  512, 512, 0, 512, 0, rowmap, mliv);
  gemm_mfma<0,2,0><<<dim3(8,256),blk,0,stream>>>(z1, aw2b, ab2, logits, 32768, 512,  1024, 512,  1024, 0, 1<<30, 0, rowmap, mliv);
  softmax_mul<<<32768,blk,0,stream>>>(logits, ccb, ccs, rowmap, mliv);
  // fused g1/g2/u layer-1 (N=1536), then ONE fused layer-2 GEMM (N=768,
  // fp16 out): per-256-col segment s uses A cols [s*512,(s+1)*512) (aseg=512);
  // cols<512 sigmoid (g1,g2), cols>=512 tanh (u)
  gemm_mfma<1,1,0><<<dim3(12,256),blk,0,stream>>>(ccs, w1cat, bcat1, zcat, 32768, 1024, 1536, 1024, 1536, 0, 1<<30, 0, rowmap, mliv);
  gemm_mfma<4,2,0><<<dim3(6,256),blk,0,stream>>>(zcat, w2cat, bcat2, zo,  32768, 512,  768,  1536, 768, 512, 1<<30, 0, rowmap, mliv);
  // memory recurrence over compact per-n prefixes
  mem_scan<<<256,blk,0,stream>>>(zo, lengths, basep, ost);
  // output MLP
  gemm_nt<64,64,1><<<dim3(12,4),blk,0,stream>>>(ost, ow1, ob1, nullptr, hid, 256, 768, 768);
  out_final<<<256,blk,0,stream>>>(hid, ow2, ob2, (float*)d_out);
}

// Round 25
// 791.412 us; speedup vs baseline: 1.1498x; 1.1498x over previous
//
#include <hip/hip_runtime.h>
#include <math.h>

#define TT 128
#define NN 256

typedef __attribute__((ext_vector_type(8))) short short8;
typedef __attribute__((ext_vector_type(8))) _Float16 half8;
typedef __attribute__((ext_vector_type(4))) float f32x4;

#define LOG2E 1.44269504088896340736f

// Fast transcendentals via hw v_exp_f32 (2^x) + v_rcp_f32 (~1ulp each; the
// library expf/tanhf carry 12-20+ instr edge handling — round-22 A/B: -94us).
__device__ __forceinline__ float exp2_(float x){ return __builtin_amdgcn_exp2f(x); }
__device__ __forceinline__ float rcp_(float x){ return __builtin_amdgcn_rcpf(x); }
__device__ __forceinline__ float sig_(float x){
  return rcp_(1.f + exp2_(-LOG2E*x));
}
__device__ __forceinline__ float tanh_(float x){
  const float e = exp2_(2.f*LOG2E*fabsf(x));     // e^{2|x|}
  const float t = 1.f - 2.f*rcp_(e + 1.f);
  return copysignf(t, x);
}
__device__ __forceinline__ float bf2f(unsigned int u){ return __uint_as_float(u<<16); }
// Integer RNE f32->bf16 (3 ops; faster than __bf16 cast which LLVM lowers
// with NaN-quieting — round-6/8 A/B: cast cost +141us total).
__device__ __forceinline__ unsigned short f2bf(float x){
  unsigned int u = __float_as_uint(x);
  u += 0x7fffu + ((u>>16)&1u);   // RNE
  return (unsigned short)(u>>16);
}
// fp32 <-> fp16 (native cvt instructions)
__device__ __forceinline__ unsigned short f2h(float x){
  _Float16 h = (_Float16)x;
  return __builtin_bit_cast(unsigned short, h);
}
__device__ __forceinline__ float h2f(unsigned short u){
  _Float16 h = __builtin_bit_cast(_Float16, u);
  return (float)h;
}
// Packed pair fp32 -> 2x fp16 (RTZ) in one instruction
__device__ __forceinline__ unsigned int cvtpk_f16(float a, float b){
  unsigned int r;
  asm("v_cvt_pkrtz_f16_f32 %0, %1, %2" : "=v"(r) : "v"(a), "v"(b));
  return r;
}

// Async global->LDS, 16B per lane (proven swizzle pair, rounds 11-24).
// GLOBAL source address is per-lane (enables the row-gather).
__device__ __forceinline__ void gld_lds16(const unsigned short* g, unsigned short* l){
  __builtin_amdgcn_global_load_lds(
      (const __attribute__((address_space(1))) unsigned int*)(g),
      (__attribute__((address_space(3))) unsigned int*)(l), 16, 0, 0);
}

// LLC-coherent (cross-XCD) access: sc0 sc1 bypasses L1+L2, coherence at Infinity Cache.
__device__ __forceinline__ short8 ld_llc8s(const unsigned short* p){
  f32x4 r;
  asm volatile("global_load_dwordx4 %0, %1, off sc0 sc1" : "=v"(r) : "v"(p) : "memory");
  return __builtin_bit_cast(short8, r);
}
__device__ __forceinline__ void st_llc_s(unsigned short* p, unsigned short v){
  unsigned int vv = v;
  asm volatile("global_store_short %0, %1, off sc0 sc1" :: "v"(p), "v"(vv) : "memory");
}

// ---------------------------------------------------------------------------
// Dead-row compaction map: rows (t,n) with t >= lengths[n] are never read by
// the final gather — ~50% of post-scan work for uniform lengths.
//   rowmap[base[n]+t] = NN + t*NN + n   (ccb CUR row; prev = -NN)
//   mliv[0] = M' = sum(lengths); mliv[1] = Mpad = roundup(M',128)
//   rowmap[M'..32768) = NN (dummy -> finite data; outputs land in unread pos)
// ---------------------------------------------------------------------------
__global__ __launch_bounds__(256) void build_map(const int* __restrict__ lengths,
    int* __restrict__ base, int* __restrict__ mliv, int* __restrict__ rowmap)
{
  const int tid = threadIdx.x;
  __shared__ int sl[256];
  __shared__ int sbase[257];
  sl[tid] = lengths[tid];
  __syncthreads();
  if (tid == 0){
    int acc = 0;
    for (int n=0;n<256;n++){ sbase[n] = acc; acc += sl[n]; }
    sbase[256] = acc;
    mliv[0] = acc;
    mliv[1] = (acc + 127) & ~127;
  }
  __syncthreads();
  base[tid] = sbase[tid];
  const int b0 = sbase[tid];
  const int len = sl[tid];
  for (int t=0;t<len;t++) rowmap[b0+t] = NN + t*NN + tid;
  const int M = sbase[256];
  for (int p = M + tid; p < TT*NN; p += 256) rowmap[p] = NN;
}

// ---------------------------------------------------------------------------
// fp32 NT GEMM (only the tiny output MLP now)
// ---------------------------------------------------------------------------
template<int BM,int BN,int ACT>
__global__ __launch_bounds__(256) void gemm_nt(const float* __restrict__ A,
    const float* __restrict__ W, const float* __restrict__ b1,
    const float* __restrict__ b2, float* __restrict__ C,
    int M, int K, int Nc)
{
  constexpr int TM = BM/16, TN = BN/16;
  __shared__ float As[BM*32];
  __shared__ float Bs[BN*32];
  const int tid = threadIdx.x;
  const int n0 = blockIdx.x*BN, m0 = blockIdx.y*BM;
  const int tx = tid & 15, ty = tid >> 4;
  float acc[TM][TN];
  #pragma unroll
  for (int r=0;r<TM;r++)
    #pragma unroll
    for (int c=0;c<TN;c++) acc[r][c]=0.f;
  const int swA = (ty & 7) << 2;
  const int swB = (tx & 7) << 2;
  for (int k0=0;k0<K;k0+=32){
    #pragma unroll
    for (int f=tid; f<BM*8; f+=256){
      const int row=f>>3, kq=f&7;
      float4 v = *(const float4*)(A + (size_t)(m0+row)*K + k0 + (kq<<2));
      *(float4*)(&As[row*32 + ((kq<<2) ^ ((row&7)<<2))]) = v;
    }
    #pragma unroll
    for (int f=tid; f<BN*8; f+=256){
      const int row=f>>3, kq=f&7;
      float4 v = *(const float4*)(W + (size_t)(n0+row)*K + k0 + (kq<<2));
      *(float4*)(&Bs[row*32 + ((kq<<2) ^ ((row&7)<<2))]) = v;
    }
    __syncthreads();
    #pragma unroll
    for (int kq=0;kq<8;kq++){
      const int k = kq<<2;
      float4 av[TM], bv[TN];
      #pragma unroll
      for (int r=0;r<TM;r++){ const int row=ty+16*r; av[r] = *(const float4*)(&As[row*32 + (k ^ swA)]); }
      #pragma unroll
      for (int c=0;c<TN;c++){ const int col=tx+16*c; bv[c] = *(const float4*)(&Bs[col*32 + (k ^ swB)]); }
      #pragma unroll
      for (int r=0;r<TM;r++)
        #pragma unroll
        for (int c=0;c<TN;c++){
          acc[r][c] += av[r].x*bv[c].x;
          acc[r][c] += av[r].y*bv[c].y;
          acc[r][c] += av[r].z*bv[c].z;
          acc[r][c] += av[r].w*bv[c].w;
        }
    }
    __syncthreads();
  }
  #pragma unroll
  for (int c=0;c<TN;c++){
    const int gcol = n0 + tx + 16*c;
    const float bias = (b1 ? b1[gcol] : 0.f) + (b2 ? b2[gcol] : 0.f);
    #pragma unroll
    for (int r=0;r<TM;r++){
      const int grow = m0 + ty + 16*r;
      float v = acc[r][c] + bias;
      if (ACT==1) v = fmaxf(v, 0.f);
      C[(size_t)grow*Nc + gcol] = v;
    }
  }
}

// ---------------------------------------------------------------------------
// bf16 MFMA NT GEMM (post-scan MLPs): C = act(A@Wb^T + bias)
// Staging via global_load_lds width-16 (proven swizzle pair, rounds 11-24).
// XCD remap: panel = (s/nx)*8 + xcd — ROUND-ROBIN panels across XCDs (the
// round-24 xcd-major map put all ~129 live compact panels on XCDs 0-4 and
// idled the rest; round-robin spreads live panels evenly while keeping all
// nx x-blocks of a panel on ONE XCD — T1 locality preserved via lin&7).
// Dead-row compaction: blocks with m0 >= Mpad (mliv[1]) exit; AMAP=1 gathers
// A rows through rowmap (attn1's ccb concat).
// ACT: 0 none, 1 relu, 2 sigmoid, 3 tanh, 4 col<512?sigmoid:tanh
// OBF: 0 fp32 out, 1 bf16 out, 2 fp16 out
// ---------------------------------------------------------------------------
template<int ACT,int OBF,int AMAP>
__global__ __launch_bounds__(256) void gemm_mfma(const unsigned short* __restrict__ A,
    const unsigned short* __restrict__ Wb, const float* __restrict__ bias,
    void* __restrict__ Cp, int M, int K, int Nc, int lda, int ldc, int aseg,
    int kswitch, int aextra,
    const int* __restrict__ rowmap, const int* __restrict__ mliv)
{
  __shared__ unsigned short sA[128*64];
  __shared__ unsigned short sB[128*64];
  const int tid = threadIdx.x;
  const int wave = tid >> 6, lane = tid & 63;
  // round-robin panel remap: lin -> (xcd, q, r) -> panel = q*8+xcd, xcol = r
  const int nx = gridDim.x;
  const int lin = blockIdx.y*nx + blockIdx.x;
  const int xcd = lin & 7, s = lin >> 3;
  const int m0 = ((s/nx)*8 + xcd)*128;
  const int n0 = (s % nx)*128;
  if (m0 >= mliv[1]) return;                        // dead panel (compact M)
  const unsigned short* Ab = A + (size_t)(n0 >> 8) * (size_t)aseg;  // block-uniform
  const int wm = (wave>>1)*64, wn = (wave&1)*64;
  const int r = lane & 15, g = lane >> 4;
  const int srow = wave*32 + (lane>>3);                  // + i*8
  const int scol = (((lane&7) ^ ((lane>>3)&7)) << 3);    // shorts
  int rml[4];
  if constexpr (AMAP){
    #pragma unroll
    for (int i=0;i<4;i++) rml[i] = rowmap[m0 + srow + i*8];
  }
  f32x4 acc[4][4];
  #pragma unroll
  for (int i=0;i<4;i++)
    #pragma unroll
    for (int j=0;j<4;j++) acc[i][j] = (f32x4){0.f,0.f,0.f,0.f};

  for (int k0 = 0; k0 < K; k0 += 64){
    if constexpr (AMAP){
      const int sel  = (k0 < kswitch);
      const int cb   = sel ? k0 : (k0 - kswitch);
      const int radj = sel ? -NN : 0;
      #pragma unroll
      for (int i=0;i<4;i++)
        gld_lds16(A + (size_t)(rml[i]+radj)*lda + cb + scol, &sA[wave*2048 + i*512]);
    } else {
      const size_t aoff = (size_t)k0 + ((k0 >= kswitch) ? (size_t)aextra : 0);
      #pragma unroll
      for (int i=0;i<4;i++)
        gld_lds16(Ab + (size_t)(m0+srow+i*8)*lda + aoff + scol, &sA[wave*2048 + i*512]);
    }
    #pragma unroll
    for (int i=0;i<4;i++)
      gld_lds16(Wb + (size_t)(n0+srow+i*8)*K + k0 + scol, &sB[wave*2048 + i*512]);
    asm volatile("s_waitcnt vmcnt(0)" ::: "memory");
    __syncthreads();
    #pragma unroll
    for (int ks=0; ks<2; ks++){
      const int cofs = ((ks*32 + g*8) ^ ((r&7)<<3));
      short8 af[4], bfr[4];
      #pragma unroll
      for (int mi=0;mi<4;mi++) af[mi]  = *(const short8*)(&sA[(wm+mi*16+r)*64 + cofs]);
      #pragma unroll
      for (int ni=0;ni<4;ni++) bfr[ni] = *(const short8*)(&sB[(wn+ni*16+r)*64 + cofs]);
      #pragma unroll
      for (int mi=0;mi<4;mi++)
        #pragma unroll
        for (int ni=0;ni<4;ni++)
          acc[mi][ni] = __builtin_amdgcn_mfma_f32_16x16x32_bf16(af[mi], bfr[ni], acc[mi][ni], 0, 0, 0);
    }
    __syncthreads();
  }
  #pragma unroll
  for (int mi=0;mi<4;mi++)
    #pragma unroll
    for (int ni=0;ni<4;ni++){
      const int col_l = wn + ni*16 + r;
      const float b = bias[n0 + col_l];
      #pragma unroll
      for (int reg=0;reg<4;reg++){
        const int row = m0 + wm + mi*16 + g*4 + reg;
        float v = acc[mi][ni][reg] + b;
        if (ACT==1) v = fmaxf(v,0.f);
        else if (ACT==2) v = sig_(v);
        else if (ACT==3) v = tanh_(v);
        else if (ACT==4) v = (n0 + col_l < 512) ? sig_(v) : tanh_(v);
        if (OBF==1)      ((unsigned short*)Cp)[(size_t)row*ldc + n0 + col_l] = f2bf(v);
        else if (OBF==2) ((unsigned short*)Cp)[(size_t)row*ldc + n0 + col_l] = f2h(v);
        else             ((float*)Cp)[(size_t)row*ldc + n0 + col_l] = v;
      }
    }
}

// ---------------------------------------------------------------------------
// Fused fp16 projection GEMMs + post-scan f2bf weight converts.
// Blocks: [0,2048) text (Nc=1024, K=768) | [2048,3072) audio (512,128) |
//         [3072,4096) vision (512,512)  | [4096,7040) f2bf converts.
// P output: fp16 GATE-INTERLEAVED.
// ---------------------------------------------------------------------------
__global__ __launch_bounds__(256) void proj_all(
    const float* __restrict__ xt, const float* __restrict__ xa, const float* __restrict__ xv,
    const unsigned short* __restrict__ wt, const unsigned short* __restrict__ wa,
    const unsigned short* __restrict__ wv,
    const float* __restrict__ bih_t, const float* __restrict__ bhh_t,
    const float* __restrict__ bih_a, const float* __restrict__ bhh_a,
    const float* __restrict__ bih_v, const float* __restrict__ bhh_v,
    unsigned short* __restrict__ Pt, unsigned short* __restrict__ Pa,
    unsigned short* __restrict__ Pv,
    const float* __restrict__ aw1, const float* __restrict__ aw2,
    const float* __restrict__ g1w1, const float* __restrict__ g2w1,
    const float* __restrict__ uw1, const float* __restrict__ g1w2,
    const float* __restrict__ g2w2, const float* __restrict__ uw2,
    unsigned short* __restrict__ wbp)
{
  __shared__ unsigned short sA[128*72];
  __shared__ unsigned short sB[128*64];
  const int tid = threadIdx.x;
  const int blk = blockIdx.x;
  if (blk >= 4096){
    // ---- f2bf: fp32 weight -> bf16 (contiguous pool), post-scan use only ----
    const int cb = blk - 4096;
    const float* src; unsigned short* dst; int i;
    if (cb < 2560){
      const int s = cb >> 9, lb = cb & 511;
      src = (s==0)?aw1:(s==1)?aw2:(s==2)?g1w1:(s==3)?g2w1:uw1;
      dst = wbp + (size_t)s*524288;
      i = lb*256 + tid;
    } else {
      const int s = (cb-2560) >> 7, lb = (cb-2560) & 127;
      src = (s==0)?g1w2:(s==1)?g2w2:uw2;
      dst = wbp + 2621440 + (size_t)s*131072;
      i = lb*256 + tid;
    }
    const float4 v = ((const float4*)src)[i];
    ushort4 o;
    o.x=f2bf(v.x); o.y=f2bf(v.y); o.z=f2bf(v.z); o.w=f2bf(v.w);
    ((ushort4*)dst)[i] = o;
    return;
  }
  const int wave = tid >> 6, lane = tid & 63;
  const float* A; const unsigned short* Wf; const float *b1, *b2; unsigned short* C;
  int K, Nc, nbs, rel, shf;
  if (blk < 2048)      { rel=blk;      A=xt; Wf=wt; b1=bih_t; b2=bhh_t; C=Pt; K=768; Nc=1024; nbs=3; shf=8; }
  else if (blk < 3072) { rel=blk-2048; A=xa; Wf=wa; b1=bih_a; b2=bhh_a; C=Pa; K=128; Nc=512;  nbs=2; shf=7; }
  else                 { rel=blk-3072; A=xv; Wf=wv; b1=bih_v; b2=bhh_v; C=Pv; K=512; Nc=512;  nbs=2; shf=7; }
  // XCD-aware remap within the region (region base is 8-aligned)
  const int xcd = rel & 7, s = rel >> 3;
  const int nxc = 1 << nbs;                  // x-cols per panel (8 / 4 / 4)
  const int m0 = (xcd*32 + s/nxc)*128;       // 32 panels per XCD
  const int n0 = (s & (nxc-1))*128;
  const int wm = (wave>>1)*64, wn = (wave&1)*64;
  const int r = lane & 15, g = lane >> 4;
  const int srow = wave*32 + (lane>>3);
  const int scol = (((lane&7) ^ ((lane>>3)&7)) << 3);
  f32x4 acc[4][4];
  #pragma unroll
  for (int i=0;i<4;i++)
    #pragma unroll
    for (int j=0;j<4;j++) acc[i][j] = (f32x4){0.f,0.f,0.f,0.f};

  for (int k0 = 0; k0 < K; k0 += 64){
    // ---- B via async gload_lds (swizzled source, linear dest) ----
    #pragma unroll
    for (int i=0;i<4;i++)
      gld_lds16(Wf + (size_t)(n0+srow+i*8)*K + k0 + scol, &sB[wave*2048 + i*512]);
    // ---- A via reg staging with fp32->fp16 convert (pad-72) ----
    #pragma unroll
    for (int j=0;j<4;j++){
      const int slot = tid + j*256;
      const int row = slot>>3, seg = (slot&7)<<3;
      const float* ap = A + (size_t)(m0+row)*K + k0 + seg;
      const float4 v0 = *(const float4*)ap;
      const float4 v1 = *(const float4*)(ap+4);
      uint4 hv;
      hv.x = cvtpk_f16(v0.x, v0.y);
      hv.y = cvtpk_f16(v0.z, v0.w);
      hv.z = cvtpk_f16(v1.x, v1.y);
      hv.w = cvtpk_f16(v1.z, v1.w);
      *(uint4*)(&sA[row*72 + seg]) = hv;
    }
    asm volatile("s_waitcnt vmcnt(0)" ::: "memory");   // drain gload_lds
    __syncthreads();
    #pragma unroll
    for (int ks=0; ks<2; ks++){
      const int cofsB = ((ks*32 + g*8) ^ ((r&7)<<3));
      half8 af[4], bfr[4];
      #pragma unroll
      for (int mi=0;mi<4;mi++) af[mi]  = *(const half8*)(&sA[(wm+mi*16+r)*72 + ks*32 + g*8]);
      #pragma unroll
      for (int ni=0;ni<4;ni++) bfr[ni] = *(const half8*)(&sB[(wn+ni*16+r)*64 + cofsB]);
      #pragma unroll
      for (int mi=0;mi<4;mi++)
        #pragma unroll
        for (int ni=0;ni<4;ni++)
          acc[mi][ni] = __builtin_amdgcn_mfma_f32_16x16x32_f16(af[mi], bfr[ni], acc[mi][ni], 0, 0, 0);
    }
    __syncthreads();
  }
  const int jm = (1<<shf) - 1;
  #pragma unroll
  for (int mi=0;mi<4;mi++)
    #pragma unroll
    for (int ni=0;ni<4;ni++){
      const int col_l = wn + ni*16 + r;
      const int col = n0 + col_l;
      const float b = b1[col] + b2[col];
      const size_t cofs = (size_t)((col & jm)<<2) + (col>>shf);
      #pragma unroll
      for (int reg=0;reg<4;reg++){
        const int row = m0 + wm + mi*16 + g*4 + reg;
        C[(size_t)row*Nc + cofs] = f2h(acc[mi][ni][reg] + b);
      }
    }
}

// ---------------------------------------------------------------------------
// Fused prep kernel. Block-range:
//   [0,1088)      Wih fp16 converts (768 + 64 + 256)
//   [1088,1280)   Whh frag reorder -> SINGLE fp16 plane (128 + 32 + 32)
//   [1280,1615)   bcat1 (6) | bcat2 (3) | hf zero (256) | flags (6) | ccz (64)
// ---------------------------------------------------------------------------
__device__ __forceinline__ void wfrag_body(const float* __restrict__ W, int H,
    int e, unsigned short* __restrict__ ff)
{
  const int nch = H >> 5;
  const int lane = e & 63;
  int r = e >> 6;
  const int ks = r % nch; r /= nch;
  const int ct = r & 3; r >>= 2;
  const int jb = r;
  const int col = ct*H + jb*16 + (lane & 15);
  const int kb  = ks*32 + (lane >> 4)*8;
  #pragma unroll
  for (int j=0;j<8;j++){
    ff[(size_t)e*8 + j] = f2h(W[(size_t)col*H + kb + j]);
  }
}

__global__ __launch_bounds__(256) void prep_all(
    const float* __restrict__ Wih_t, const float* __restrict__ Wih_a,
    const float* __restrict__ Wih_v,
    const float* __restrict__ Whh_t, const float* __restrict__ Whh_a,
    const float* __restrict__ Whh_v,
    const float* __restrict__ g1b1, const float* __restrict__ g2b1,
    const float* __restrict__ ub1,
    const float* __restrict__ g1b2, const float* __restrict__ g2b2,
    const float* __restrict__ ub2,
    unsigned short* __restrict__ wbp, unsigned short* __restrict__ wfp,
    float* __restrict__ bcat1, float* __restrict__ bcat2,
    float* __restrict__ hfZ,
    unsigned int* __restrict__ flags, unsigned short* __restrict__ ccb)
{
  const int blk = blockIdx.x, tid = threadIdx.x;
  if (blk < 1088){
    // ---- Wih fp32 -> fp16 (single array per modality) ----
    const int rel = blk;
    const float* src; unsigned short* dst; int i;
    if (rel < 768)      { src=Wih_t; dst=wbp+3014656; i=rel*256+tid; }
    else if (rel < 832) { src=Wih_a; dst=wbp+3801088; i=(rel-768)*256+tid; }
    else                { src=Wih_v; dst=wbp+3866624; i=(rel-832)*256+tid; }
    const float4 v = ((const float4*)src)[i];
    ushort4 h;
    h.x=f2h(v.x); h.y=f2h(v.y); h.z=f2h(v.z); h.w=f2h(v.w);
    ((ushort4*)dst)[i] = h;
  } else if (blk < 1280){
    // ---- Whh MFMA-B-frag reorder (single fp16 plane) ----
    const int rel = blk - 1088;
    if (rel < 128)      wfrag_body(Whh_t, 256, rel*256+tid,       wfp);
    else if (rel < 160) wfrag_body(Whh_a, 128, (rel-128)*256+tid, wfp+262144);
    else                wfrag_body(Whh_v, 128, (rel-160)*256+tid, wfp+327680);
  } else {
    // ---- misc: bias concats + zeroing ----
    const int rel = blk - 1280;
    if (rel < 6){
      const int idx = rel*256 + tid;
      float v = (idx<512) ? g1b1[idx] : (idx<1024) ? g2b1[idx-512] : ub1[idx-1024];
      bcat1[idx] = v;
    } else if (rel < 9){
      const int idx = (rel-6)*256 + tid;
      float v = (idx<256) ? g1b2[idx] : (idx<512) ? g2b2[idx-256] : ub2[idx-512];
      bcat2[idx] = v;
    } else if (rel < 265){
      const int i = (rel-9)*256 + tid;
      ((float4*)hfZ)[i] = (float4){0.f,0.f,0.f,0.f};
    } else if (rel < 271){
      const int i = (rel-265)*256 + tid;
      ((uint4*)flags)[i] = (uint4){0u,0u,0u,0u};
    } else {
      // zero ccb pad rows (t = -1): NN*512 ushorts
      const int i = (rel-271)*256 + tid;
      ((uint4*)ccb)[i] = (uint4){0u,0u,0u,0u};
    }
  }
}

// ---------------------------------------------------------------------------
// Persistent LSTM scan (round-3 proven protocol). fp16 SINGLE-PLANE h +
// fp16 gate-interleaved P + hw-exp2 transcendentals. Byte-identical to the
// round-23 build (902us).
// ---------------------------------------------------------------------------
__global__ __launch_bounds__(256) void lstm_scan(
    const unsigned short* __restrict__ Pt, const unsigned short* __restrict__ Pa,
    const unsigned short* __restrict__ Pv,
    const unsigned short* __restrict__ wtfF, const unsigned short* __restrict__ wafF,
    const unsigned short* __restrict__ wvfF,
    const int* __restrict__ lengths,
    unsigned short* __restrict__ hfT, unsigned short* __restrict__ hfA, unsigned short* __restrict__ hfV,
    unsigned short* __restrict__ ccb, float* __restrict__ o_stage,
    unsigned int* __restrict__ flags)
{
  __shared__ unsigned short sWh[16384];   // 32 KB (text max: 4ct x 8ks x 64 x 8, fp16)
  __shared__ float sG[4*32*17];           // gate scratch, pad 17
  const int tid = threadIdx.x;
  const int b = blockIdx.x;
  const int rb = b & 7, jb = b >> 3;
  const int n0 = rb * 32;
  const unsigned short* P; const unsigned short* wfF; unsigned short* hf;
  int H, j0, off, grp, mem, gsz, jbl;
  if (jb < 16)      { P=Pt; wfF=wtfF; hf=hfT; H=256; jbl=jb;    off=0;   grp=rb;    mem=jbl; gsz=16; }
  else if (jb < 24) { P=Pa; wfF=wafF; hf=hfA; H=128; jbl=jb-16; off=256; grp=8+rb;  mem=jbl; gsz=8;  }
  else              { P=Pv; wfF=wvfF; hf=hfV; H=128; jbl=jb-24; off=384; grp=16+rb; mem=jbl; gsz=8;  }
  j0 = jbl*16;
  const int nch = H >> 5;
  const int G4 = 4*H;
  const size_t planeSz = (size_t)NN*H;    // ushorts per plane
  unsigned int* myflag = &flags[(grp*16+mem)<<4];
  unsigned int* gflags = &flags[(grp*16)<<4];

  // one-time W frag staging to LDS (contiguous copy, fp16 single plane)
  {
    const unsigned short* srcF = wfF + (size_t)jbl*4*nch*512;
    const int nseg = 4*nch*64;
    for (int s = tid; s < nseg; s += 256)
      *(uint4*)(&sWh[s*8]) = *(const uint4*)(srcF + (size_t)s*8);
  }
  const int tx = tid & 15, ty = tid >> 4;
  const int n_a = n0 + ty, n_b = n0 + ty + 16;
  const int last_a = lengths[n_a] - 1, last_b = lengths[n_b] - 1;
  const int jcol = j0 + tx;
  // producer h-frag element indices (within a plane)
  const int ksP = jcol >> 5, kqP = (jcol>>3)&3, jP = jcol&7;
  const size_t eA = ((size_t)((rb*2+0)*nch + ksP)*64 + (ty|(kqP<<4)))*8 + jP;   // row ty   (rt 0)
  const size_t eB = ((size_t)((rb*2+1)*nch + ksP)*64 + (ty|(kqP<<4)))*8 + jP;   // row ty+16(rt 1)
  const int wave = tid >> 6, lane = tid & 63;
  const int rt = wave >> 1, ct0 = (wave&1)*2, ct1 = ct0+1;
  const size_t fragBase = ((size_t)(rb*2+rt)*nch)*512 + (size_t)lane*8;   // + ks*512
  float c_a = 0.f, c_b = 0.f;
  uint2 pA, pB;
  {
    pA = *(const uint2*)(P + (size_t)n_a*G4 + (size_t)jcol*4);
    pB = *(const uint2*)(P + (size_t)n_b*G4 + (size_t)jcol*4);
  }
  __syncthreads();

  for (int t = 0; t < TT; ++t){
    const int cur = t & 1, nxt = cur ^ 1;
    const unsigned short* hH = hf + (size_t)cur*planeSz;
    // ---- A-frags direct from LLC into registers (single fp16 plane) ----
    short8 ah[8];
    #pragma unroll
    for (int ks=0; ks<8; ks++) if (ks < nch)
      ah[ks] = ld_llc8s(hH + fragBase + (size_t)ks*512);
    asm volatile("s_waitcnt vmcnt(0)" ::: "memory");
    // ---- early P prefetch for t+1 (ONE uint2 each): completes under MFMA ----
    uint2 pA2, pB2;
    if (t < TT-1){
      pA2 = *(const uint2*)(P + ((size_t)(t+1)*NN + n_a)*G4 + (size_t)jcol*4);
      pB2 = *(const uint2*)(P + ((size_t)(t+1)*NN + n_b)*G4 + (size_t)jcol*4);
    }
    __builtin_amdgcn_sched_barrier(0);   // pin prefetch issue before MFMA
    // ---- MFMA: gates tile 16x32 (2 col-tiles per wave, fp16) ----
    f32x4 acc0 = (f32x4){0.f,0.f,0.f,0.f}, acc1 = (f32x4){0.f,0.f,0.f,0.f};
    #pragma unroll
    for (int ks=0; ks<8; ks++) if (ks < nch){
      const int b0 = ((ct0*nch+ks)*64 + lane)*8;
      const int b1 = ((ct1*nch+ks)*64 + lane)*8;
      const half8 w0 = *(const half8*)(&sWh[b0]);
      const half8 w1 = *(const half8*)(&sWh[b1]);
      const half8 a  = __builtin_bit_cast(half8, ah[ks]);
      acc0 = __builtin_amdgcn_mfma_f32_16x16x32_f16(a, w0, acc0, 0,0,0);
      acc1 = __builtin_amdgcn_mfma_f32_16x16x32_f16(a, w1, acc1, 0,0,0);
    }
    // gate write: C row = (lane>>4)*4+reg, col = lane&15
    #pragma unroll
    for (int reg=0; reg<4; reg++){
      const int grow = rt*16 + (lane>>4)*4 + reg;
      sG[(ct0*32+grow)*17 + (lane&15)] = acc0[reg];
      sG[(ct1*32+grow)*17 + (lane&15)] = acc1[reg];
    }
    __syncthreads();
    // ---- cell update: only the h-frag stores issue here ----
    const size_t pbase = (size_t)t*NN;
    const int col = off + jcol;
    unsigned short cA, cB; float h2a, h2b;
    {
      unsigned short* dH = hf + (size_t)nxt*planeSz;
      float gi = sG[(0*32+ty)*17+tx] + h2f((unsigned short)(pA.x & 0xffffu));
      float gf = sG[(1*32+ty)*17+tx] + h2f((unsigned short)(pA.x >> 16));
      float gg = sG[(2*32+ty)*17+tx] + h2f((unsigned short)(pA.y & 0xffffu));
      float go = sG[(3*32+ty)*17+tx] + h2f((unsigned short)(pA.y >> 16));
      float c2 = sig_(gf)*c_a + sig_(gi)*tanh_(gg);
      c_a = c2;
      h2a = sig_(go)*tanh_(c2);
      st_llc_s(dH + eA, f2h(h2a));
      cA = f2bf(c2);

      gi = sG[(0*32+ty+16)*17+tx] + h2f((unsigned short)(pB.x & 0xffffu));
      gf = sG[(1*32+ty+16)*17+tx] + h2f((unsigned short)(pB.x >> 16));
      gg = sG[(2*32+ty+16)*17+tx] + h2f((unsigned short)(pB.y & 0xffffu));
      go = sG[(3*32+ty+16)*17+tx] + h2f((unsigned short)(pB.y >> 16));
      c2 = sig_(gf)*c_b + sig_(gi)*tanh_(gg);
      c_b = c2;
      h2b = sig_(go)*tanh_(c2);
      st_llc_s(dH + eB, f2h(h2b));
      cB = f2bf(c2);
    }
    // ---- per-group barrier through LLC (no cache maintenance) ----
    if (t < TT-1){
      const unsigned want = (unsigned)(t+1);
      asm volatile("s_waitcnt vmcnt(0)" ::: "memory");  // own h stores at LLC
      __syncthreads();
      if (tid == 0)
        __hip_atomic_store(myflag, want, __ATOMIC_RELAXED, __HIP_MEMORY_SCOPE_SYSTEM);
      // deferred ccb / o_stage stores: overlap with the poll (single cc write)
      ccb[(NN + pbase + n_a)*512 + col] = cA;
      if (t == last_a) o_stage[(size_t)n_a*768 + col] = h2a;
      ccb[(NN + pbase + n_b)*512 + col] = cB;
      if (t == last_b) o_stage[(size_t)n_b*768 + col] = h2b;
      __builtin_amdgcn_sched_barrier(0);
      if (tid < gsz){
        while (__hip_atomic_load(&gflags[tid<<4], __ATOMIC_RELAXED, __HIP_MEMORY_SCOPE_SYSTEM) < want)
          __builtin_amdgcn_s_sleep(1);
      }
      __syncthreads();
      pA = pA2; pB = pB2;
    } else {
      ccb[(NN + pbase + n_a)*512 + col] = cA;
      if (t == last_a) o_stage[(size_t)n_a*768 + col] = h2a;
      ccb[(NN + pbase + n_b)*512 + col] = cB;
      if (t == last_b) o_stage[(size_t)n_b*768 + col] = h2b;
    }
  }
}

// ---------------------------------------------------------------------------
// Row softmax over 1024 + multiply: ccs = cc_tt * softmax(logits), COMPACT
// rows. Row index = compact pos; cc read through rowmap (cur row; prev =
// cur - NN). Rows >= Mpad skipped.
// ---------------------------------------------------------------------------
__global__ __launch_bounds__(256) void softmax_mul(const unsigned short* __restrict__ logits,
    const unsigned short* __restrict__ ccb, unsigned short* __restrict__ outp,
    const int* __restrict__ rowmap, const int* __restrict__ mliv)
{
  const int row = blockIdx.x, tid = threadIdx.x;
  if (row >= mliv[1]) return;
  const size_t base = (size_t)row*1024 + (tid<<2);
  const ushort4 lv = *(const ushort4*)(logits + base);
  const float v0 = h2f(lv.x), v1 = h2f(lv.y), v2 = h2f(lv.z), v3 = h2f(lv.w);
  float m = fmaxf(fmaxf(v0,v1),fmaxf(v2,v3));
  #pragma unroll
  for (int o=32;o;o>>=1) m = fmaxf(m, __shfl_xor(m, o));
  __shared__ float sm[4]; __shared__ float ss[4];
  const int wid = tid>>6, lane = tid&63;
  if (lane==0) sm[wid]=m;
  __syncthreads();
  m = fmaxf(fmaxf(sm[0],sm[1]),fmaxf(sm[2],sm[3]));
  const float e0 = exp2_((v0-m)*LOG2E), e1 = exp2_((v1-m)*LOG2E);
  const float e2 = exp2_((v2-m)*LOG2E), e3 = exp2_((v3-m)*LOG2E);
  float s = e0+e1+e2+e3;
  #pragma unroll
  for (int o=32;o;o>>=1) s += __shfl_xor(s, o);
  if (lane==0) ss[wid]=s;
  __syncthreads();
  const float inv = rcp_(ss[0]+ss[1]+ss[2]+ss[3]);
  // mapped cc read: cols<512 -> prev ccb row; cols>=512 -> cur ccb row
  const int cur = rowmap[row];
  const size_t cbase = (tid < 128)
      ? ((size_t)(cur - NN)*512 + (tid<<2))
      : ((size_t)cur*512 + (tid<<2) - 512);
  const uint2 c2 = *(const uint2*)(ccb + cbase);
  const float c0 = bf2f(c2.x&0xffffu), c1 = bf2f(c2.x>>16);
  const float c2f= bf2f(c2.y&0xffffu), c3 = bf2f(c2.y>>16);
  uint2 o2;
  o2.x = (unsigned int)f2bf(c0*e0*inv) | ((unsigned int)f2bf(c1*e1*inv)<<16);
  o2.y = (unsigned int)f2bf(c2f*e2*inv) | ((unsigned int)f2bf(c3*e3*inv)<<16);
  *(uint2*)(outp + base) = o2;
}

// ---------------------------------------------------------------------------
// Memory recurrence over COMPACT rows: block n reads zo rows base[n]..+len-1
// (contiguous), runs exactly len steps; result is m at the last valid step.
// ---------------------------------------------------------------------------
__global__ __launch_bounds__(256) void mem_scan(const unsigned short* __restrict__ zo,
    const int* __restrict__ lengths, const int* __restrict__ base,
    float* __restrict__ o_stage)
{
  const int n = blockIdx.x, j = threadIdx.x;
  const int len = lengths[n];
  const size_t b0 = (size_t)base[n];
  float m = 0.f;
  for (int t0=0; t0<len; t0+=8){
    unsigned short a[8], bb[8], c[8];
    #pragma unroll
    for (int q=0;q<8;q++){
      const size_t row = (b0 + t0 + q)*768;   // may over-read into slot pad (safe)
      a[q]  = zo[row+j];
      bb[q] = zo[row+256+j];
      c[q]  = zo[row+512+j];
    }
    #pragma unroll
    for (int q=0;q<8;q++)
      if (t0+q < len) m = h2f(a[q])*m + h2f(bb[q])*h2f(c[q]);
  }
  o_stage[(size_t)n*768 + 512 + j] = m;
}

// ---------------------------------------------------------------------------
__global__ __launch_bounds__(256) void out_final(const float* __restrict__ hidden,
    const float* __restrict__ ow2, const float* __restrict__ ob2, float* __restrict__ out)
{
  const int n = blockIdx.x, tid = threadIdx.x;
  const float* hr = hidden + (size_t)n*768;
  float s = hr[tid]*ow2[tid] + hr[tid+256]*ow2[tid+256] + hr[tid+512]*ow2[tid+512];
  #pragma unroll
  for (int o=32;o;o>>=1) s += __shfl_xor(s, o);
  __shared__ float sw[4];
  const int wid=tid>>6, lane=tid&63;
  if (lane==0) sw[wid]=s;
  __syncthreads();
  if (tid==0) out[n] = sw[0]+sw[1]+sw[2]+sw[3] + ob2[0];
}

__global__ void ws_sentinel(float* out, float mb){ out[threadIdx.x] = mb; }

// ---------------------------------------------------------------------------
extern "C" void kernel_launch(void* const* d_in, const int* in_sizes, int n_in,
                              void* d_out, int out_size, void* d_ws, size_t ws_size,
                              hipStream_t stream)
{
  const float* x_text   = (const float*)d_in[0];
  const float* x_audio  = (const float*)d_in[1];
  const float* x_vision = (const float*)d_in[2];
  const int*   lengths  = (const int*)d_in[3];
  const float* Wih_t=(const float*)d_in[4],  *Whh_t=(const float*)d_in[5];
  const float* bih_t=(const float*)d_in[6],  *bhh_t=(const float*)d_in[7];
  const float* Wih_a=(const float*)d_in[8],  *Whh_a=(const float*)d_in[9];
  const float* bih_a=(const float*)d_in[10], *bhh_a=(const float*)d_in[11];
  const float* Wih_v=(const float*)d_in[12], *Whh_v=(const float*)d_in[13];
  const float* bih_v=(const float*)d_in[14], *bhh_v=(const float*)d_in[15];
  const float* aw1=(const float*)d_in[16], *ab1=(const float*)d_in[17];
  const float* aw2=(const float*)d_in[18], *ab2=(const float*)d_in[19];
  const float* g1w1=(const float*)d_in[20], *g1b1=(const float*)d_in[21];
  const float* g1w2=(const float*)d_in[22], *g1b2=(const float*)d_in[23];
  const float* g2w1=(const float*)d_in[24], *g2b1=(const float*)d_in[25];
  const float* g2w2=(const float*)d_in[26], *g2b2=(const float*)d_in[27];
  const float* uw1 =(const float*)d_in[28], *ub1 =(const float*)d_in[29];
  const float* uw2 =(const float*)d_in[30], *ub2 =(const float*)d_in[31];
  const float* ow1 =(const float*)d_in[32], *ob1 =(const float*)d_in[33];
  const float* ow2 =(const float*)d_in[34], *ob2 =(const float*)d_in[35];
  (void)in_sizes; (void)n_in; (void)out_size;

  // ---- workspace layout (float units). Peak ~350 MB ----
  const size_t oPt = 0;            // slot 33.55M : Pt(fp16 interleaved) -> logits(fp16) -> zcat(bf16)
  const size_t oPa = 33554432;     // slot 16.78M : Pa(fp16) -> z1(bf16) -> zo(fp16)
  const size_t oPv = 50331648;     // slot 16.78M : Pv(fp16) -> ccs(bf16)
  const size_t oCC = 67108864;     // 8.46M  : ccb [(T+1)*N, 512] bf16 (single-stored)
  const size_t oHF = 83886080;     // h frag pools (fp16 single-plane; half used)
  const size_t oOS = 84148224;     // 196608 : o_stage [256,768]
  const size_t oHID= 84344832;     // 196608
  const size_t oWB = 84541440;     // bf16/fp16 weight pool (2,621,440 f)
  const size_t oBC = 87162880;     // bcat1 1536 f + bcat2 768 f
  const size_t oBAR= 87165184;     // flags 6144 ints
  const size_t oWF = 87171328;     // Whh frag pool (fp16 single; half used)
  const size_t oMAP= 87564544;     // rowmap 32768 + base 256 + mliv 16 ints
  const size_t totalf = 87597584;

  if (ws_size < totalf * sizeof(float)) {
    ws_sentinel<<<1,256,0,stream>>>((float*)d_out, (float)(ws_size >> 20));
    return;
  }

  float* ws = (float*)d_ws;
  unsigned short* Pt = (unsigned short*)(ws + oPt);    // fp16 interleaved [32768,1024]
  unsigned short* Pa = (unsigned short*)(ws + oPa);    // fp16 interleaved [32768,512]
  unsigned short* Pv = (unsigned short*)(ws + oPv);    // fp16 interleaved [32768,512]
  unsigned short* ccb = (unsigned short*)(ws + oCC);   // [(T+1)*NN, 512] bf16
  unsigned short* hfT = (unsigned short*)(ws + oHF);            // [2 par][65536] fp16
  unsigned short* hfA = (unsigned short*)(ws + oHF + 131072);   // [2][32768]
  unsigned short* hfV = (unsigned short*)(ws + oHF + 196608);   // [2][32768]
  float* ost = ws + oOS; float* hid = ws + oHID;
  unsigned int* flags = (unsigned int*)(ws + oBAR);
  // weight pool (shorts)
  unsigned short* wbp   = (unsigned short*)(ws + oWB);
  unsigned short* aw1b  = wbp;                 // 524288
  unsigned short* aw2b  = wbp + 524288;        // 524288
  unsigned short* w1cat = wbp + 1048576;       // 1572864 (g1w1|g2w1|uw1)
  unsigned short* w2cat = wbp + 2621440;       // 393216 (g1w2|g2w2|uw2)
  unsigned short* wtih_f= wbp + 3014656;       // 786432 (fp16)
  unsigned short* waih_f= wbp + 3801088;       // 65536  (fp16)
  unsigned short* wvih_f= wbp + 3866624;       // 262144 (fp16, end 4128768)
  float* bcat1 = ws + oBC;
  float* bcat2 = ws + oBC + 1536;
  // Whh frag arrays (fp16 single-plane)
  unsigned short* wfp  = (unsigned short*)(ws + oWF);
  unsigned short* wtfF = wfp;                  // 262144
  unsigned short* wafF = wfp + 262144;         // 65536
  unsigned short* wvfF = wfp + 327680;         // 65536 (end 393216)
  // compaction map
  int* rowmap = (int*)(ws + oMAP);             // 32768
  int* basep  = rowmap + 32768;                // 256
  int* mliv   = basep + 256;                   // 16
  // post-scan aliases
  unsigned short* logits = (unsigned short*)(ws + oPt);   // fp16 (compact rows)
  unsigned short* z1     = (unsigned short*)(ws + oPa);
  unsigned short* ccs    = (unsigned short*)(ws + oPv);
  unsigned short* zcat   = (unsigned short*)(ws + oPt);
  unsigned short* zo     = (unsigned short*)(ws + oPa);   // fp16 [32768,768]

  dim3 blk(256);

  // prep kernel (Wih fp16, Whh fp16 frags, bias concats, zeroing)
  prep_all<<<1615,blk,0,stream>>>(Wih_t, Wih_a, Wih_v, Whh_t, Whh_a, Whh_v,
                                  g1b1, g2b1, ub1, g1b2, g2b2, ub2,
                                  wbp, wfp, bcat1, bcat2, (float*)hfT, flags, ccb);

  // dead-row compaction map (lengths only; ~50% of post-scan work eliminated)
  build_map<<<1,blk,0,stream>>>(lengths, basep, mliv, rowmap);

  // input projections (fp16 interleaved P out, XCD-swizzled) + f2bf converts
  proj_all<<<7040,blk,0,stream>>>(x_text, x_audio, x_vision,
                                  wtih_f, waih_f, wvih_f,
                                  bih_t, bhh_t, bih_a, bhh_a, bih_v, bhh_v,
                                  Pt, Pa, Pv,
                                  aw1, aw2, g1w1, g2w1, uw1, g1w2, g2w2, uw2,
                                  wbp);

  // sequential LSTM scan (fp16 MFMA + LLC frag exchange)
  {
    void* args[] = {(void*)&Pt,(void*)&Pa,(void*)&Pv,
                    (void*)&wtfF,(void*)&wafF,(void*)&wvfF,
                    (void*)&lengths,(void*)&hfT,(void*)&hfA,(void*)&hfV,
                    (void*)&ccb,(void*)&ost,(void*)&flags};
    hipError_t e = hipLaunchCooperativeKernel((const void*)lstm_scan,
                      dim3(256), dim3(256), args, 0, stream);
    if (e != hipSuccess)
      lstm_scan<<<256,blk,0,stream>>>(Pt,Pa,Pv,wtfF,wafF,wvfF,
                                      lengths,hfT,hfA,hfV,ccb,ost,flags);
  }

  // attention MLP on COMPACT rows (bf16 MFMA, gload_lds staging, round-robin
  // XCD panels). attn1 gathers ccb via rowmap (AMAP=1): k<512 -> prev row
  // (map-NN) col k; k>=512 -> cur row col k-512.
  gemm_mfma<1,1,1><<<dim3(4,256),blk,0,stream>>>(ccb, aw1b, ab1, z1,     32768, 1024, 512,  512, 512, 0, 512, 0, rowmap, mliv);
  gemm_mfma<0,2,0><<<dim3(8,256),blk,0,stream>>>(z1, aw2b, ab2, logits, 32768, 512,  1024, 512,  1024, 0, 1<<30, 0, rowmap, mliv);
  softmax_mul<<<32768,blk,0,stream>>>(logits, ccb, ccs, rowmap, mliv);
  // fused g1/g2/u layer-1 (N=1536), then ONE fused layer-2 GEMM (N=768,
  // fp16 out): per-256-col segment s uses A cols [s*512,(s+1)*512) (aseg=512);
  // cols<512 sigmoid (g1,g2), cols>=512 tanh (u)
  gemm_mfma<1,1,0><<<dim3(12,256),blk,0,stream>>>(ccs, w1cat, bcat1, zcat, 32768, 1024, 1536, 1024, 1536, 0, 1<<30, 0, rowmap, mliv);
  gemm_mfma<4,2,0><<<dim3(6,256),blk,0,stream>>>(zcat, w2cat, bcat2, zo,  32768, 512,  768,  1536, 768, 512, 1<<30, 0, rowmap, mliv);
  // memory recurrence over compact per-n prefixes
  mem_scan<<<256,blk,0,stream>>>(zo, lengths, basep, ost);
  // output MLP
  gemm_nt<64,64,1><<<dim3(12,4),blk,0,stream>>>(ost, ow1, ob1, nullptr, hid, 256, 768, 768);
  out_final<<<256,blk,0,stream>>>(hid, ow2, ob2, (float*)d_out);
}